// Round 8
// baseline (237.967 us; speedup 1.0000x reference)
//
#include <hip/hip_runtime.h>

#define Bn 512
#define Tn 1024
#define Nn 64
#define WB 4      // waves per batch: 64 segments, wave h owns columns m = 16h+n
#define BURN 16   // burn-in steps (verified: R3 scalar + R6/R7 MFMA, absmax 0.0)

typedef float    f4  __attribute__((ext_vector_type(4)));
typedef __fp16   pk2 __attribute__((ext_vector_type(2)));   // cvt_pkrtz result type
typedef __fp16   pk4 __attribute__((ext_vector_type(4)));
typedef __fp16   pk8 __attribute__((ext_vector_type(8)));
typedef _Float16 h8v __attribute__((ext_vector_type(8)));

__device__ __forceinline__ float wave_sum(float v) {
#pragma unroll
    for (int off = 32; off >= 1; off >>= 1) v += __shfl_xor(v, off, 64);
    return v;
}

// One wave = 16 segments (MFMA columns) of batch b; WB=4 waves cover the
// 64 segments of one batch. U' = E^T diag-scaled P, 8 mfma/step, no LDS
// (B k-map chosen == C/D layout so B packs in-register; A uses same k-map,
// contraction invariant). Depth-8 register ring prefetches emit rows.
// R7 measured ~72us at 2 waves/CU with ~85% memory stall -> this round
// quadruples resident waves (2048 = 8/CU) and cuts steps/wave 80 -> 32.
// Early segments (a_m <= BURN+1) clamp start to 1 and become EXACT-prefix
// columns: init exp(strans), L0 recorded at start+k == a_m. No approximation.
__global__ __launch_bounds__(64) void crf_mfma(
    const float* __restrict__ emit,
    const int*   __restrict__ target,
    const int*   __restrict__ mask,
    const float* __restrict__ trans,
    const float* __restrict__ strans,
    const float* __restrict__ etrans,
    float*       __restrict__ out)
{
    const int lane = threadIdx.x;
    const int n = lane & 15;          // column within this wave's MFMA
    const int g = lane >> 4;          // lane group
    const int b = blockIdx.x & (Bn - 1);
    const int h = blockIdx.x >> 9;    // 0..3; blocks b, b+512, ... share an XCD
    const int m = 16 * h + n;         // global segment id, 0..63
    const size_t ebase = (size_t)b * Tn * Nn;

    // ---- A fragments with k-map k = 32hh + 16*(j>>2) + 4g + (j&3)
    // Et[row][k] = exp(trans[k][row]); row = 16r + n
    h8v A[4][2];
#pragma unroll
    for (int r = 0; r < 4; ++r)
#pragma unroll
        for (int hh = 0; hh < 2; ++hh) {
            h8v a;
#pragma unroll
            for (int j = 0; j < 8; ++j) {
                int kk = 32 * hh + 16 * (j >> 2) + 4 * g + (j & 3);
                a[j] = (_Float16)__expf(trans[kk * Nn + 16 * r + n]);
            }
            A[r][hh] = a;
        }

    // ---- len = popcount of prefix mask
    const int* mrow = mask + (size_t)b * Tn;
    int lsum = 0;
#pragma unroll
    for (int k = 0; k < Tn / Nn; ++k) lsum += mrow[k * Nn + lane];
#pragma unroll
    for (int off = 32; off >= 1; off >>= 1) lsum += __shfl_xor(lsum, off, 64);
    const int len = lsum;                       // in [512, 1024]

    // ---- segment bounds for column m
    const int a0v   = (m * len) >> 6;
    const int a1v   = ((m + 1) * len) >> 6;
    int start = a0v - BURN; if (start < 1) start = 1;   // start==1 -> exact prefix
    const int tendv = a1v - 1;                  // last step t for this column
    const int maxk  = ((len + 63) >> 6) + BURN; // covers all columns' records

    // ---- end weights: only global segment 63 weights its final colsum
    float wsel[4][4];
#pragma unroll
    for (int r = 0; r < 4; ++r) {
        f4 ee = *(const f4*)(emit + ebase + (size_t)(len - 1) * Nn + 16 * r + 4 * g);
        f4 et = *(const f4*)(etrans + 16 * r + 4 * g);
#pragma unroll
        for (int c = 0; c < 4; ++c)
            wsel[r][c] = (m == 63) ? __expf(ee[c] + et[c]) : 1.0f;
    }

    // ---- U init (C/D layout: row = 16r + 4g + c, col n) = u_{start-1}.
    // start==1 (m==0 or clamped early segment): exact u_0 = exp(strans).
    float U[4][4];
#pragma unroll
    for (int r = 0; r < 4; ++r) {
        f4 st = *(const f4*)(strans + 16 * r + 4 * g);
#pragma unroll
        for (int c = 0; c < 4; ++c)
            U[r][c] = (start == 1) ? __expf(st[c]) : 1.0f;
    }

    int   S = 0;
    float L0 = 0.0f, contrib = 0.0f;

    // ---- depth-8 prefetch ring: rbuf[q] holds raw emit row (start + 8*kb + q - 1)
    f4 rbuf[8][4];
#pragma unroll
    for (int d = 0; d < 8; ++d) {
        int tr = start - 1 + d; if (tr > Tn - 1) tr = Tn - 1;
        const f4* p = (const f4*)(emit + ebase + (size_t)tr * Nn);
#pragma unroll
        for (int r = 0; r < 4; ++r) rbuf[d][r] = p[4 * r + g];
    }

    const f4 zero4 = {0.f, 0.f, 0.f, 0.f};
    const int nkb = (maxk + 7) >> 3;            // extra steps harmless:
                                                // rescale bounds U, records latch on ==

    for (int kb = 0; kb < nkb; ++kb) {
#pragma unroll
        for (int q = 0; q < 8; ++q) {
            const int k = 8 * kb + q;

            // W for this step (row start+k-1), then refill slot q (row start+k+7)
            float Wx[4][4];
#pragma unroll
            for (int r = 0; r < 4; ++r)
#pragma unroll
                for (int c = 0; c < 4; ++c) Wx[r][c] = __expf(rbuf[q][r][c]);
            {
                int tr = start + k + 7; if (tr > Tn - 1) tr = Tn - 1;
                const f4* p = (const f4*)(emit + ebase + (size_t)tr * Nn);
#pragma unroll
                for (int r = 0; r < 4; ++r) rbuf[q][r] = p[4 * r + g];
            }

            // burn-in end: U = u_{a0v-1}; record L0, reset S (per-column k!)
            bool br = m && ((start + k) == a0v);
            if (__any(br)) {
                float cs = 0.f;
#pragma unroll
                for (int r = 0; r < 4; ++r)
#pragma unroll
                    for (int c = 0; c < 4; ++c) cs += U[r][c];
                cs += __shfl_xor(cs, 16, 64);
                cs += __shfl_xor(cs, 32, 64);
                float l0v = __logf(cs);
                if (br) { L0 = l0v; S = 0; }
            }

            // per-column rescale: mx = col max -> mx*2^mk in [1,2)
            float m0 = fmaxf(fmaxf(U[0][0], U[0][1]), fmaxf(U[0][2], U[0][3]));
            float m1 = fmaxf(fmaxf(U[1][0], U[1][1]), fmaxf(U[1][2], U[1][3]));
            float m2 = fmaxf(fmaxf(U[2][0], U[2][1]), fmaxf(U[2][2], U[2][3]));
            float m3 = fmaxf(fmaxf(U[3][0], U[3][1]), fmaxf(U[3][2], U[3][3]));
            float mx = fmaxf(fmaxf(m0, m1), fmaxf(m2, m3));
            mx = fmaxf(mx, __shfl_xor(mx, 16, 64));
            mx = fmaxf(mx, __shfl_xor(mx, 32, 64));
            const int mk = 127 - ((__float_as_int(mx) >> 23) & 0xff);
            S += mk;
            const float sc2 = __int_as_float((127 + mk) << 23);   // 2^mk

            // p = U * 2^mk * W -> fp16, packed in-register as B (k-map above)
            float P_[4][4];
#pragma unroll
            for (int r = 0; r < 4; ++r)
#pragma unroll
                for (int c = 0; c < 4; ++c) P_[r][c] = U[r][c] * sc2 * Wx[r][c];

            pk2 c00 = __builtin_amdgcn_cvt_pkrtz(P_[0][0], P_[0][1]);
            pk2 c01 = __builtin_amdgcn_cvt_pkrtz(P_[0][2], P_[0][3]);
            pk2 c10 = __builtin_amdgcn_cvt_pkrtz(P_[1][0], P_[1][1]);
            pk2 c11 = __builtin_amdgcn_cvt_pkrtz(P_[1][2], P_[1][3]);
            pk2 c20 = __builtin_amdgcn_cvt_pkrtz(P_[2][0], P_[2][1]);
            pk2 c21 = __builtin_amdgcn_cvt_pkrtz(P_[2][2], P_[2][3]);
            pk2 c30 = __builtin_amdgcn_cvt_pkrtz(P_[3][0], P_[3][1]);
            pk2 c31 = __builtin_amdgcn_cvt_pkrtz(P_[3][2], P_[3][3]);
            pk4 b0lo = __builtin_shufflevector(c00, c01, 0, 1, 2, 3);
            pk4 b0hi = __builtin_shufflevector(c10, c11, 0, 1, 2, 3);
            pk4 b1lo = __builtin_shufflevector(c20, c21, 0, 1, 2, 3);
            pk4 b1hi = __builtin_shufflevector(c30, c31, 0, 1, 2, 3);
            pk8 b0p = __builtin_shufflevector(b0lo, b0hi, 0, 1, 2, 3, 4, 5, 6, 7);
            pk8 b1p = __builtin_shufflevector(b1lo, b1hi, 0, 1, 2, 3, 4, 5, 6, 7);
            h8v B0 = __builtin_bit_cast(h8v, b0p);
            h8v B1 = __builtin_bit_cast(h8v, b1p);

            // U' = Et x P  (8 MFMA, no LDS anywhere)
#pragma unroll
            for (int r = 0; r < 4; ++r) {
                f4 acc = __builtin_amdgcn_mfma_f32_16x16x32_f16(A[r][0], B0, zero4, 0, 0, 0);
                acc     = __builtin_amdgcn_mfma_f32_16x16x32_f16(A[r][1], B1, acc,   0, 0, 0);
#pragma unroll
                for (int c = 0; c < 4; ++c) U[r][c] = acc[c];
            }

            // segment-end record (fires on ~2-3 iterations total)
            bool rec = (start + k) == tendv;
            if (__any(rec)) {
                float cs = 0.f;
#pragma unroll
                for (int r = 0; r < 4; ++r)
#pragma unroll
                    for (int c = 0; c < 4; ++c) cs = fmaf(U[r][c], wsel[r][c], cs);
                cs += __shfl_xor(cs, 16, 64);
                cs += __shfl_xor(cs, 32, 64);
                float lv = __logf(cs);
                if (rec) contrib = lv - (float)S * 0.6931471805599453f - L0;
            }
        }
    }

    // 4 lanes per column hold identical contrib -> /4
    float tot = wave_sum(contrib) * 0.25f;

    // ---- gold-path score: computed once per batch, by wave h==0
    float sc = 0.0f;
    const int* trow = target + (size_t)b * Tn;
    if (h == 0) {
#pragma unroll
        for (int k = 0; k < Tn / Nn; ++k) {
            int t = k * Nn + lane;
            if (t < len) {
                int gT = trow[t];
                sc += emit[ebase + (size_t)t * Nn + gT];
                if (t > 0) sc += trans[trow[t - 1] * Nn + gT];
            }
        }
        sc = wave_sum(sc);
    }

    if (lane == 0) {
        float add = tot;
        if (h == 0) add -= sc + strans[trow[0]] + etrans[trow[len - 1]];
        atomicAdd(out, add * (1.0f / (float)Bn));
    }
}

extern "C" void kernel_launch(void* const* d_in, const int* in_sizes, int n_in,
                              void* d_out, int out_size, void* d_ws, size_t ws_size,
                              hipStream_t stream) {
    const float* emit   = (const float*)d_in[0];
    const int*   target = (const int*)d_in[1];
    const int*   mask   = (const int*)d_in[2];
    const float* trans  = (const float*)d_in[3];
    const float* strans = (const float*)d_in[4];
    const float* etrans = (const float*)d_in[5];
    float* out = (float*)d_out;

    (void)hipMemsetAsync(out, 0, sizeof(float), stream);
    crf_mfma<<<Bn * WB, Nn, 0, stream>>>(emit, target, mask, trans, strans, etrans, out);
}